// Round 5
// baseline (62902.179 us; speedup 1.0000x reference)
//
#include <hip/hip_runtime.h>
#include <cstddef>
#include <cstdint>
#include <cmath>

#define NBLK 256
#define NTHR 512

// ---- dynamic LDS float offsets ----
#define L_WIH   0        // [6][1152]  rows (sh*3+gate): i,g,o for col 2blk+sh
#define L_WOUT  6912     // [8][1024]  score rows 8blk..8blk+7
#define L_WT    15104    // [2][512]   W_attn^T rows 2blk,2blk+1
#define L_VVS   16128    // [640]      staged vv[fb] + lse/amax broadcast
#define L_FA    16768    // [16384]    flash scratch
#define L_TOT   33152    // floats = 129.5 KiB

// ---- ws float offsets ----
#define WS_BAR   0        // 1088 dwords: [0]=root, [32]=gen, [64+g*32]=groups
#define WS_HDN   1088     // [64][512]
#define WS_VV    33856    // [64][512]
#define WS_SC    66624    // [64][2048]
#define WS_PACC  197696   // [2][64][512]
#define WS_PS    263232   // [2][64]
#define WS_EMB   263360   // [64][128]
#define WS_PART  271552   // [64][256][4] {m, se, idxf, pad}

__device__ __forceinline__ float dot4(float4 a, float4 b) {
    return a.x*b.x + a.y*b.y + a.z*b.z + a.w*b.w;
}

// sc1 (agent-scope) stores: write-through to the coherence point.
__device__ __forceinline__ void st1(float* p, float v) {
    __hip_atomic_store(p, v, __ATOMIC_RELAXED, __HIP_MEMORY_SCOPE_AGENT);
}
__device__ __forceinline__ void st2(float* p, float a, float b) {
    union { unsigned long long u; float2 f; } c; c.f = make_float2(a, b);
    __hip_atomic_store((unsigned long long*)p, c.u,
        __ATOMIC_RELAXED, __HIP_MEMORY_SCOPE_AGENT);
}

// Hierarchical grid barrier: 32 groups of 8 -> root -> gen (all monotonic,
// relaxed). Exit does one agent-scope ACQUIRE load per thread -> buffer_inv,
// making subsequent PLAIN cached loads coherent with sc1 stores (R4-proven).
__device__ __forceinline__ void gridbar(unsigned* bar, unsigned iter) {
    asm volatile("s_waitcnt vmcnt(0) lgkmcnt(0)" ::: "memory");
    __syncthreads();
    if (threadIdx.x == 0) {
        const unsigned g = blockIdx.x >> 3;
        unsigned p = __hip_atomic_fetch_add(bar + 64 + g * 32, 1u,
                        __ATOMIC_RELAXED, __HIP_MEMORY_SCOPE_AGENT);
        if (p == iter * 8u - 1u) {
            unsigned rp = __hip_atomic_fetch_add(bar, 1u,
                        __ATOMIC_RELAXED, __HIP_MEMORY_SCOPE_AGENT);
            if (rp == iter * 32u - 1u)
                __hip_atomic_store(bar + 32, iter, __ATOMIC_RELAXED,
                                   __HIP_MEMORY_SCOPE_AGENT);
        }
        while (__hip_atomic_load(bar + 32, __ATOMIC_RELAXED,
                                 __HIP_MEMORY_SCOPE_AGENT) < iter)
            __builtin_amdgcn_s_sleep(1);
    }
    __syncthreads();
    (void)__hip_atomic_load(bar + 32, __ATOMIC_ACQUIRE, __HIP_MEMORY_SCOPE_AGENT);
    asm volatile("" ::: "memory");
}

__global__ __launch_bounds__(NTHR, 2) void nmt_fused(
    const float* __restrict__ enc, const int* __restrict__ mask,
    const float* __restrict__ embTab, const float* __restrict__ Wih,
    const float* __restrict__ bih, const float* __restrict__ bhh,
    const float* __restrict__ Wa, const float* __restrict__ Wout,
    const float* __restrict__ bout, float* __restrict__ out,
    float* __restrict__ ws)
{
    extern __shared__ float smem[];

    const int blk = blockIdx.x;
    const int tid = threadIdx.x;

    unsigned* bar = (unsigned*)ws;
    float* hdnw = ws + WS_HDN;
    float* vvw  = ws + WS_VV;
    float* scw  = ws + WS_SC;
    float* pacc = ws + WS_PACC;
    float* ps   = ws + WS_PS;
    float* embw = ws + WS_EMB;
    float* partw= ws + WS_PART;

    unsigned bi = 0;

    // ---------------- prologue: weights -> LDS ----------------
    {
        #pragma unroll
        for (int s = 0; s < 6; ++s) {
            const int sh = s / 3, gate = s % 3;
            const int col = 2 * blk + sh;
            const int grow = (gate == 0) ? col : (gate == 1) ? 1024 + col : 1536 + col;
            for (int off = tid; off < 1152; off += NTHR)
                smem[L_WIH + s * 1152 + off] = Wih[(size_t)grow * 1152 + off];
        }
        #pragma unroll
        for (int s = 0; s < 8; ++s)
            for (int off = tid; off < 1024; off += NTHR)
                smem[L_WOUT + s * 1024 + off] = Wout[(size_t)(8 * blk + s) * 1024 + off];
        #pragma unroll
        for (int s = 0; s < 2; ++s)
            smem[L_WT + s * 512 + tid] = Wa[(size_t)tid * 512 + (2 * blk + s)];
    }
    // thread-role decode (shared by P1/P2)
    const int q  = tid & 15;          // k-split 16
    const int rh = (tid >> 4) & 1;    // row-half
    const int bl = tid >> 5;          // b-group (4 b's)
    const int hi = (q >> 3) & 1;      // bank-conflict half-swap

    // P1 biases (col = 2blk + rh)
    const int colP1 = 2 * blk + rh;
    const float biB = bih[colP1]        + bhh[colP1];
    const float bgB = bih[1024 + colP1] + bhh[1024 + colP1];
    const float boB = bih[1536 + colP1] + bhh[1536 + colP1];
    // P2 biases (rows 8blk + rh*4 + rr)
    float bo_r[4];
    #pragma unroll
    for (int rr = 0; rr < 4; ++rr) bo_r[rr] = bout[8 * blk + rh * 4 + rr];

    // state init (blocks 0..63): ctx0 -> pacc slot1, ps slot1 = 1, emb = 0
    if (blk < 64) {
        const int b = blk;
        int* ism = (int*)(smem + L_FA);
        ism[tid] = mask[b * 512 + tid];
        __syncthreads();
        for (int off = 256; off; off >>= 1) {
            if (tid < off) ism[tid] += ism[tid + off];
            __syncthreads();
        }
        int tl = ism[0] - 1;
        if (tl < 0) tl = 0;
        st1(pacc + 32768 + b * 512 + tid, enc[((size_t)(b * 512 + tl)) * 512 + tid]);
        if (tid == 0) st1(ps + 64 + b, 1.f);
        if (tid < 128) st1(embw + b * 128 + tid, 0.f);
    }
    gridbar(bar, ++bi);

    // ---------------- main loop ----------------
    for (int t = 0; t < 512; ++t) {
        const int cur = t & 1;
        float* paccC = pacc + cur * 32768;
        const float* paccP = pacc + (cur ^ 1) * 32768;
        float* psC = ps + cur * 64;
        const float* psP = ps + (cur ^ 1) * 64;

        // ===== P1: gates GEMM (LDS weights, R=4 batch) + LSTM -> hdn =====
        {
            // zero next-slot accumulators for P3's atomics
            if (tid < 128) st1(paccC + blk * 128 + tid, 0.f);
            if (blk == 0 && tid < 64) st1(psC + tid, 0.f);

            float invs[4];
            #pragma unroll
            for (int i = 0; i < 4; ++i) {
                float sden = psP[4 * bl + i];
                invs[i] = (sden != 0.f) ? 1.f / sden : 0.f;
            }

            float acc[3][4];
            #pragma unroll
            for (int gq = 0; gq < 3; ++gq)
                #pragma unroll
                for (int i = 0; i < 4; ++i) acc[gq][i] = 0.f;

            #pragma unroll
            for (int c = 0; c < 9; ++c) {
                float4 xA[4], xB[4];
                #pragma unroll
                for (int i = 0; i < 4; ++i) {
                    const int b = 4 * bl + i;
                    const float* src;
                    if (c == 0)      src = embw + b * 128 + q * 8;
                    else if (c <= 4) src = paccP + b * 512 + (c - 1) * 128 + q * 8;
                    else             src = enc + ((size_t)(b * 512 + t)) * 512
                                               + (c - 5) * 128 + q * 8;
                    float4 a = *(const float4*)(src + 4 * hi);
                    float4 bq = *(const float4*)(src + 4 - 4 * hi);
                    if (c >= 1 && c <= 4) {
                        const float sc_ = invs[i];
                        a.x *= sc_; a.y *= sc_; a.z *= sc_; a.w *= sc_;
                        bq.x *= sc_; bq.y *= sc_; bq.z *= sc_; bq.w *= sc_;
                    }
                    xA[i] = a; xB[i] = bq;
                }
                #pragma unroll
                for (int gq = 0; gq < 3; ++gq) {
                    const float* wl = smem + L_WIH + (rh * 3 + gq) * 1152
                                    + c * 128 + q * 8;
                    float4 w0 = *(const float4*)(wl + 4 * hi);
                    float4 w1 = *(const float4*)(wl + 4 - 4 * hi);
                    #pragma unroll
                    for (int i = 0; i < 4; ++i)
                        acc[gq][i] += dot4(w0, xA[i]) + dot4(w1, xB[i]);
                }
            }
            #pragma unroll
            for (int gq = 0; gq < 3; ++gq)
                #pragma unroll
                for (int i = 0; i < 4; ++i) {
                    #pragma unroll
                    for (int off = 1; off < 16; off <<= 1)
                        acc[gq][i] += __shfl_xor(acc[gq][i], off);
                }
            if (q == 0) {
                #pragma unroll
                for (int i = 0; i < 4; ++i) {
                    const int b = 4 * bl + i;
                    float ig = acc[0][i] + biB;
                    float gg = acc[1][i] + bgB;
                    float og = acc[2][i] + boB;
                    float cv = (1.f / (1.f + expf(-ig))) * tanhf(gg);
                    float hv = (1.f / (1.f + expf(-og))) * tanhf(cv);
                    st1(hdnw + b * 512 + colP1, hv);
                }
            }
        }
        gridbar(bar, ++bi);

        // ===== P2: scores (4 rows) + vv (1 col) per row-half, R=4 batch =====
        {
            float invs[4];
            #pragma unroll
            for (int i = 0; i < 4; ++i) {
                float sden = psP[4 * bl + i];
                invs[i] = (sden != 0.f) ? 1.f / sden : 0.f;
            }

            float acc_s[4][4], acc_v[4];
            #pragma unroll
            for (int rr = 0; rr < 4; ++rr)
                #pragma unroll
                for (int i = 0; i < 4; ++i) acc_s[rr][i] = 0.f;
            #pragma unroll
            for (int i = 0; i < 4; ++i) acc_v[i] = 0.f;

            #pragma unroll
            for (int c = 0; c < 8; ++c) {
                float4 xA[4], xB[4];
                #pragma unroll
                for (int i = 0; i < 4; ++i) {
                    const int b = 4 * bl + i;
                    const float* src = (c < 4)
                        ? (hdnw + b * 512 + c * 128 + q * 8)
                        : (paccP + b * 512 + (c - 4) * 128 + q * 8);
                    float4 a = *(const float4*)(src + 4 * hi);
                    float4 bq = *(const float4*)(src + 4 - 4 * hi);
                    if (c >= 4) {
                        const float sc_ = invs[i];
                        a.x *= sc_; a.y *= sc_; a.z *= sc_; a.w *= sc_;
                        bq.x *= sc_; bq.y *= sc_; bq.z *= sc_; bq.w *= sc_;
                    }
                    xA[i] = a; xB[i] = bq;
                }
                #pragma unroll
                for (int rr = 0; rr < 4; ++rr) {
                    const float* wl = smem + L_WOUT + (rh * 4 + rr) * 1024
                                    + c * 128 + q * 8;
                    float4 w0 = *(const float4*)(wl + 4 * hi);
                    float4 w1 = *(const float4*)(wl + 4 - 4 * hi);
                    #pragma unroll
                    for (int i = 0; i < 4; ++i)
                        acc_s[rr][i] += dot4(w0, xA[i]) + dot4(w1, xB[i]);
                }
                if (c < 4) {
                    const float* wl = smem + L_WT + rh * 512 + c * 128 + q * 8;
                    float4 w0 = *(const float4*)(wl + 4 * hi);
                    float4 w1 = *(const float4*)(wl + 4 - 4 * hi);
                    #pragma unroll
                    for (int i = 0; i < 4; ++i)
                        acc_v[i] += dot4(w0, xA[i]) + dot4(w1, xB[i]);
                }
            }
            #pragma unroll
            for (int rr = 0; rr < 4; ++rr)
                #pragma unroll
                for (int i = 0; i < 4; ++i) {
                    #pragma unroll
                    for (int off = 1; off < 16; off <<= 1)
                        acc_s[rr][i] += __shfl_xor(acc_s[rr][i], off);
                }
            #pragma unroll
            for (int i = 0; i < 4; ++i) {
                #pragma unroll
                for (int off = 1; off < 16; off <<= 1)
                    acc_v[i] += __shfl_xor(acc_v[i], off);
            }
            if (q == 0) {
                #pragma unroll
                for (int i = 0; i < 4; ++i) {
                    const int b = 4 * bl + i;
                    float s0 = acc_s[0][i] + bo_r[0];
                    float s1 = acc_s[1][i] + bo_r[1];
                    float s2 = acc_s[2][i] + bo_r[2];
                    float s3 = acc_s[3][i] + bo_r[3];
                    float* sb = scw + b * 2048 + 8 * blk + rh * 4;
                    st2(sb, s0, s1); st2(sb + 2, s2, s3);
                    st1(vvw + b * 512 + 2 * blk + rh, acc_v[i]);
                    // per-8 partial lse/argmax (merged across rh via shfl)
                    float m4 = s0; int i4 = 0;
                    if (s1 > m4) { m4 = s1; i4 = 1; }
                    if (s2 > m4) { m4 = s2; i4 = 2; }
                    if (s3 > m4) { m4 = s3; i4 = 3; }
                    int gidx = 8 * blk + rh * 4 + i4;
                    float se4 = expf(s0 - m4) + expf(s1 - m4)
                              + expf(s2 - m4) + expf(s3 - m4);
                    float mo  = __shfl_xor(m4, 16);
                    float seo = __shfl_xor(se4, 16);
                    int   io  = __shfl_xor(gidx, 16);
                    float M = fmaxf(m4, mo);
                    float se = se4 * expf(m4 - M) + seo * expf(mo - M);
                    int idx = (mo > m4 || (mo == m4 && io < gidx)) ? io : gidx;
                    if (rh == 0) {
                        float* pp = partw + ((size_t)b * 256 + blk) * 4;
                        st2(pp, M, se);
                        st2(pp + 2, (float)idx, 0.f);
                    }
                }
            }
        }
        gridbar(bar, ++bi);

        // ===== P3: lse combine + logp + emb + flash partial (atomics) =====
        {
            const int fb = blk >> 2, r = blk & 3;

            // stage vv[fb] into LDS
            if (tid < 256) {
                float2 v = *(const float2*)(vvw + fb * 512 + tid * 2);
                *(float2*)(smem + L_VVS + tid * 2) = v;
            }
            // one-wave lse/argmax combine over 256 partials
            if (tid < 64) {
                float m = -3.4e38f, se = 0.f; int idx = 0x7fffffff;
                #pragma unroll
                for (int kk = 0; kk < 4; ++kk) {
                    const float* pp = partw + ((size_t)fb * 256 + tid + kk * 64) * 4;
                    float2 a = *(const float2*)pp;
                    float2 ci = *(const float2*)(pp + 2);
                    float M = fmaxf(m, a.x);
                    se = se * expf(m - M) + a.y * expf(a.x - M);
                    int i2 = (int)ci.x;
                    idx = (a.x > m || (a.x == m && i2 < idx)) ? i2 : idx;
                    m = M;
                }
                #pragma unroll
                for (int off = 1; off < 64; off <<= 1) {
                    float mo = __shfl_xor(m, off);
                    float seo = __shfl_xor(se, off);
                    int io = __shfl_xor(idx, off);
                    float M = fmaxf(m, mo);
                    se = se * expf(m - M) + seo * expf(mo - M);
                    idx = (mo > m || (mo == m && io < idx)) ? io : idx;
                    m = M;
                }
                if (tid == 0) {
                    smem[L_VVS + 512] = m + logf(se);
                    smem[L_VVS + 513] = (float)idx;
                }
            }
            __syncthreads();
            const float lse = smem[L_VVS + 512];
            const int amax = (int)smem[L_VVS + 513];

            // logp quarter for this block
            {
                float v = scw[fb * 2048 + r * 512 + tid] - lse;
                st1(out + ((size_t)(fb * 512 + t)) * 2048 + r * 512 + tid, v);
            }
            // greedy embedding feed for t+1
            if (r == 0 && tid < 64) {
                const float* er = embTab + (size_t)amax * 128 + tid * 2;
                st2(embw + fb * 128 + tid * 2, er[0], er[1]);
            }

            // flash partial over rows [r*128, r*128+128)
            const int w = tid >> 6, lane = tid & 63, l = lane & 15, g = lane >> 4;
            float4 v4[8];
            #pragma unroll
            for (int j = 0; j < 8; ++j)
                v4[j] = *(const float4*)(smem + L_VVS + l * 32 + j * 4);

            float4 a4[8];
            #pragma unroll
            for (int j = 0; j < 8; ++j) a4[j] = make_float4(0.f, 0.f, 0.f, 0.f);
            float s_loc = 0.f;
            for (int p = 0; p < 4; ++p) {
                const int ta = r * 128 + p * 32 + w * 4 + g;
                const int mk = mask[fb * 512 + ta];
                const float* er = enc + ((size_t)(fb * 512 + ta)) * 512 + l * 32;
                float4 e4[8];
                #pragma unroll
                for (int j = 0; j < 8; ++j) e4[j] = *(const float4*)(er + j * 4);
                float d = 0.f;
                #pragma unroll
                for (int j = 0; j < 8; ++j) d += dot4(e4[j], v4[j]);
                d += __shfl_xor(d, 1);
                d += __shfl_xor(d, 2);
                d += __shfl_xor(d, 4);
                d += __shfl_xor(d, 8);
                const float pw = mk ? expf(d) : 0.f;
                s_loc += pw;
                #pragma unroll
                for (int j = 0; j < 8; ++j) {
                    a4[j].x += pw * e4[j].x; a4[j].y += pw * e4[j].y;
                    a4[j].z += pw * e4[j].z; a4[j].w += pw * e4[j].w;
                }
            }
            float* fa = smem + L_FA;
            __syncthreads();
            {
                float* row = fa + (w * 4 + g) * 512 + l * 32;
                #pragma unroll
                for (int j = 0; j < 8; ++j)
                    ((float4*)row)[(j + l) & 7] = a4[j];
            }
            __syncthreads();
            {
                const int lh = tid >> 5, jh = (tid >> 2) & 7, comp = tid & 3;
                const int off0 = lh * 32 + ((jh + lh) & 7) * 4 + comp;
                float a = 0.f;
                #pragma unroll
                for (int R = 0; R < 32; ++R) a += fa[R * 512 + off0];
                atomicAdd(paccC + fb * 512 + tid, a);
            }
            __syncthreads();
            if (l == 0) fa[w * 4 + g] = s_loc;
            __syncthreads();
            if (tid == 0) {
                float s = 0.f;
                #pragma unroll
                for (int R = 0; R < 32; ++R) s += fa[R];
                atomicAdd(psC + fb, s);
            }
        }
        gridbar(bar, ++bi);
    }
}

extern "C" void kernel_launch(void* const* d_in, const int* in_sizes, int n_in,
                              void* d_out, int out_size, void* d_ws, size_t ws_size,
                              hipStream_t stream)
{
    const float* enc    = (const float*)d_in[0];
    const int*   mask   = (const int*)  d_in[1];
    const float* embTab = (const float*)d_in[2];
    const float* Wih    = (const float*)d_in[3];
    const float* bih    = (const float*)d_in[4];
    const float* bhh    = (const float*)d_in[5];
    const float* Wa     = (const float*)d_in[6];
    // d_in[7] = b_attn: cancelled by softmax (constant over t)
    const float* Wout   = (const float*)d_in[8];
    const float* bout   = (const float*)d_in[9];
    float* out = (float*)d_out;
    float* wsf = (float*)d_ws;

    (void)hipFuncSetAttribute((const void*)nmt_fused,
                              hipFuncAttributeMaxDynamicSharedMemorySize, 163840);

    // zero barrier state (root, gen, 32 group counters)
    hipMemsetAsync(d_ws, 0, 4352, stream);

    void* args[] = {
        (void*)&enc, (void*)&mask, (void*)&embTab, (void*)&Wih, (void*)&bih,
        (void*)&bhh, (void*)&Wa, (void*)&Wout, (void*)&bout, (void*)&out,
        (void*)&wsf
    };
    hipLaunchCooperativeKernel((void*)nmt_fused, dim3(NBLK), dim3(NTHR),
                               args, (unsigned)(L_TOT * sizeof(float)), stream);
}